// Round 1
// baseline (276.304 us; speedup 1.0000x reference)
//
#include <hip/hip_runtime.h>
#include <math.h>

// Problem constants (from reference): B=2, N=256, C=5, H=4, DH=8, HID=32, FF=20
#define BB 2
#define NN 256
#define CC 5
#define HIDD 32

// NOTE on dead code in the reference: x1 starts as zeros => q1=0, y10/yI/yU/yX=0,
// so logits use only q0·(k00*yk00). The final output depends only on the x0
// (scalar) channel: o1/v1/d1/h1/f1 never reach `out`. We therefore compute only
// the scalar path: phi chunks k00 (R2 cols 0:32) and v00 (R2 cols 192:224).

__device__ __forceinline__ float gelu_tanh(float x) {
    float x3 = x * x * x;
    return 0.5f * x * (1.0f + tanhf(0.7978845608028654f * (x + 0.044715f * x3)));
}
__device__ __forceinline__ float sgnf(float x) {
    return (x > 0.f) ? 1.f : ((x < 0.f) ? -1.f : 0.f);
}

// ---- Kernel 1: pack adjacency rows into 4x uint64 bitmasks per row ----
__global__ void pack_adj(const int* __restrict__ adj, unsigned long long* __restrict__ bits) {
    int t = blockIdx.x * blockDim.x + threadIdx.x; // 0..B*N-1
    if (t >= BB * NN) return;
    const int* row = adj + (size_t)t * NN;
    unsigned long long w[4] = {0ull, 0ull, 0ull, 0ull};
    for (int j = 0; j < NN; j++)
        if (row[j] != 0) w[j >> 6] |= (1ull << (j & 63));
    for (int k = 0; k < 4; k++) bits[t * 4 + k] = w[k];
}

// ---- Kernel 2: per-node prep: x0n = norm_se3 scalar part; project q0, yk00, yv00 ----
__global__ void node_prep(const float* __restrict__ feats,
                          const float* __restrict__ Wq0,   // (C,32)
                          const float* __restrict__ Mk0,   // (C,32)
                          const float* __restrict__ Mv0,   // (C,32)
                          const float* __restrict__ gnA0,  // (C)
                          const float* __restrict__ bnA0,  // (C)
                          float* __restrict__ q0, float* __restrict__ yk, float* __restrict__ yv) {
    int node = blockIdx.x;      // b*N + i
    int hd = threadIdx.x;       // 0..31
    const float* f = feats + node * CC;
    float n0[CC], x0n[CC];
    float mu = 0.f;
    for (int c = 0; c < CC; c++) { n0[c] = fabsf(f[c]); mu += n0[c]; }
    mu *= (1.0f / CC);
    float var = 0.f;
    for (int c = 0; c < CC; c++) { float d = n0[c] - mu; var += d * d; }
    var *= (1.0f / CC);
    float sd = sqrtf(var) + 1e-8f;
    for (int c = 0; c < CC; c++) {
        float ln = (n0[c] - mu) / sd * gnA0[c] + bnA0[c];
        x0n[c] = sgnf(f[c]) * gelu_tanh(ln);
    }
    float q = 0.f, k = 0.f, v = 0.f;
    for (int c = 0; c < CC; c++) {
        q = fmaf(x0n[c], Wq0[c * HIDD + hd], q);
        k = fmaf(x0n[c], Mk0[c * HIDD + hd], k);
        v = fmaf(x0n[c], Mv0[c * HIDD + hd], v);
    }
    q0[node * HIDD + hd] = q;
    yk[node * HIDD + hd] = k;
    yv[node * HIDD + hd] = v;
}

// ---- Kernel 3: fused edge MLP + masked softmax attention + per-node epilogue ----
// One block per (b,i); thread j = neighbor index.
__global__ __launch_bounds__(256) void edge_attn(
    const float* __restrict__ coors,
    const float* __restrict__ R1,   // (32)
    const float* __restrict__ rb1,  // (32)
    const float* __restrict__ R2,   // (32,384)
    const float* __restrict__ rb2,  // (384)
    const float* __restrict__ q0g, const float* __restrict__ ykg, const float* __restrict__ yvg,
    const unsigned long long* __restrict__ bits,
    const float* __restrict__ feats,
    const float* __restrict__ Wo0,  // (32,5)
    const float* __restrict__ gnF0, const float* __restrict__ bnF0, // (C)
    const float* __restrict__ Wf10, // (C,20)
    const float* __restrict__ Wf20, // (20,C)
    float* __restrict__ xfin)       // (B*N,5)  final scalar features
{
    int node = blockIdx.x;
    int b = node >> 8, i = node & 255;
    int tid = threadIdx.x;
    int j = tid;
    int lane = tid & 63, wave = tid >> 6;

    __shared__ float Rk[32][32];   // R2[w][0:32]
    __shared__ float Rv[32][32];   // R2[w][192:224]
    __shared__ float rbk[32], rbv[32], sR1[32], srb1[32], q0s[32];
    __shared__ unsigned long long sbits[4];
    __shared__ float wredm[4][4], wreds[4][4];
    __shared__ float hm[4], hs[4];
    __shared__ float o0w[4][32];
    __shared__ float o0s[32];

    for (int e = tid; e < 1024; e += 256) {
        int w = e >> 5, d = e & 31;
        Rk[w][d] = R2[w * 384 + d];
        Rv[w][d] = R2[w * 384 + 192 + d];
    }
    if (tid < 32) {
        rbk[tid] = rb2[tid];
        rbv[tid] = rb2[192 + tid];
        sR1[tid] = R1[tid];
        srb1[tid] = rb1[tid];
        q0s[tid] = q0g[node * 32 + tid];
    }
    if (tid < 4) sbits[tid] = bits[node * 4 + tid];
    __syncthreads();

    // dist(i,j)
    float dx = coors[(b * NN + j) * 3 + 0] - coors[(b * NN + i) * 3 + 0];
    float dy = coors[(b * NN + j) * 3 + 1] - coors[(b * NN + i) * 3 + 1];
    float dz = coors[(b * NN + j) * 3 + 2] - coors[(b * NN + i) * 3 + 2];
    float dist = sqrtf(dx * dx + dy * dy + dz * dz + 1e-12f);

    // hidden = relu(dist*R1 + rb1)
    float hid[32];
#pragma unroll
    for (int w = 0; w < 32; w++) hid[w] = fmaxf(fmaf(dist, sR1[w], srb1[w]), 0.f);

    // logits: lg[h] = sum_d k00[h*8+d] * q0[h*8+d] * yk00[j,h*8+d]
    const float* ykp = ykg + (size_t)(b * NN + j) * 32;
    float lg[4] = {0.f, 0.f, 0.f, 0.f};
#pragma unroll
    for (int hd = 0; hd < 32; hd++) {
        float kk = rbk[hd];
#pragma unroll
        for (int w = 0; w < 32; w++) kk = fmaf(hid[w], Rk[w][hd], kk);
        lg[hd >> 3] = fmaf(kk * q0s[hd], ykp[hd], lg[hd >> 3]);
    }

    // adjm mask: direct edge | shared neighbor | diagonal
    unsigned long long myb0 = bits[(b * NN + j) * 4 + 0];
    unsigned long long myb1 = bits[(b * NN + j) * 4 + 1];
    unsigned long long myb2 = bits[(b * NN + j) * 4 + 2];
    unsigned long long myb3 = bits[(b * NN + j) * 4 + 3];
    bool direct = (sbits[j >> 6] >> (j & 63)) & 1ull;
    unsigned long long shr = (sbits[0] & myb0) | (sbits[1] & myb1) | (sbits[2] & myb2) | (sbits[3] & myb3);
    bool ok = direct || (shr != 0ull) || (i == j);
    const float invs = 0.35355339059327379f; // 1/sqrt(8)
#pragma unroll
    for (int h = 0; h < 4; h++) lg[h] = ok ? lg[h] * invs : -1e9f;

    // block softmax over j for each of 4 heads
    float m[4], p[4], attn[4];
#pragma unroll
    for (int h = 0; h < 4; h++) {
        float v = lg[h];
        for (int off = 32; off; off >>= 1) v = fmaxf(v, __shfl_xor(v, off, 64));
        if (lane == 0) wredm[h][wave] = v;
    }
    __syncthreads();
    if (tid < 4) hm[tid] = fmaxf(fmaxf(wredm[tid][0], wredm[tid][1]), fmaxf(wredm[tid][2], wredm[tid][3]));
    __syncthreads();
#pragma unroll
    for (int h = 0; h < 4; h++) { m[h] = hm[h]; p[h] = expf(lg[h] - m[h]); }
#pragma unroll
    for (int h = 0; h < 4; h++) {
        float v = p[h];
        for (int off = 32; off; off >>= 1) v += __shfl_xor(v, off, 64);
        if (lane == 0) wreds[h][wave] = v;
    }
    __syncthreads();
    if (tid < 4) hs[tid] = wreds[tid][0] + wreds[tid][1] + wreds[tid][2] + wreds[tid][3];
    __syncthreads();
#pragma unroll
    for (int h = 0; h < 4; h++) attn[h] = p[h] / hs[h];

    // o0[hd] = sum_j attn[h]*v00[hd]*yv00[j,hd]
    const float* yvp = yvg + (size_t)(b * NN + j) * 32;
#pragma unroll
    for (int hd = 0; hd < 32; hd++) {
        float vv = rbv[hd];
#pragma unroll
        for (int w = 0; w < 32; w++) vv = fmaf(hid[w], Rv[w][hd], vv);
        float pv = attn[hd >> 3] * vv * yvp[hd];
        for (int off = 32; off; off >>= 1) pv += __shfl_xor(pv, off, 64);
        if (lane == 0) o0w[wave][hd] = pv;
    }
    __syncthreads();
    if (tid < 32) o0s[tid] = o0w[0][tid] + o0w[1][tid] + o0w[2][tid] + o0w[3][tid];
    __syncthreads();

    // per-node epilogue: d0 = o0@Wo0; residual; norm_se3 scalar; FF scalar; residual
    if (tid == 0) {
        float x0a[5];
        for (int c = 0; c < 5; c++) {
            float d0 = 0.f;
            for (int hd = 0; hd < 32; hd++) d0 = fmaf(o0s[hd], Wo0[hd * 5 + c], d0);
            x0a[c] = feats[node * 5 + c] + d0;
        }
        float n0[5], mu = 0.f;
        for (int c = 0; c < 5; c++) { n0[c] = fabsf(x0a[c]); mu += n0[c]; }
        mu *= 0.2f;
        float var = 0.f;
        for (int c = 0; c < 5; c++) { float d = n0[c] - mu; var += d * d; }
        var *= 0.2f;
        float sd = sqrtf(var) + 1e-8f;
        float xf[5];
        for (int c = 0; c < 5; c++) {
            float ln = (n0[c] - mu) / sd * gnF0[c] + bnF0[c];
            xf[c] = sgnf(x0a[c]) * gelu_tanh(ln);
        }
        float h0[20];
        for (int f = 0; f < 20; f++) {
            float s = 0.f;
            for (int c = 0; c < 5; c++) s = fmaf(xf[c], Wf10[c * 20 + f], s);
            h0[f] = gelu_tanh(s);
        }
        for (int c = 0; c < 5; c++) {
            float f0 = 0.f;
            for (int f = 0; f < 20; f++) f0 = fmaf(h0[f], Wf20[f * 5 + c], f0);
            xfin[node * 5 + c] = x0a[c] + f0;
        }
    }
}

// ---- Kernel 4: mean-pool over nodes + 2-layer MLP head ----
__global__ void head_mlp(const float* __restrict__ xfin,
                         const float* __restrict__ Wh1, const float* __restrict__ bh1,
                         const float* __restrict__ Wh2, const float* __restrict__ bh2,
                         float* __restrict__ out) {
    __shared__ float pooled[10];
    __shared__ float hdn[2][128];
    int tid = threadIdx.x;
    if (tid < 10) {
        int b = tid / 5, c = tid % 5;
        float s = 0.f;
        for (int i = 0; i < NN; i++) s += xfin[(b * NN + i) * 5 + c];
        pooled[tid] = s * (1.0f / NN);
    }
    __syncthreads();
    {
        int b = tid >> 7, k = tid & 127;
        float s = bh1[k];
        for (int c = 0; c < 5; c++) s = fmaf(pooled[b * 5 + c], Wh1[c * 128 + k], s);
        hdn[b][k] = fmaxf(s, 0.f);
    }
    __syncthreads();
    if (tid < 18) {
        int b = tid / 9, o = tid % 9;
        float s = bh2[o];
        for (int k = 0; k < 128; k++) s = fmaf(hdn[b][k], Wh2[k * 9 + o], s);
        out[b * 9 + o] = s;
    }
}

extern "C" void kernel_launch(void* const* d_in, const int* in_sizes, int n_in,
                              void* d_out, int out_size, void* d_ws, size_t ws_size,
                              hipStream_t stream) {
    const float* feats = (const float*)d_in[0];
    const float* coors = (const float*)d_in[1];
    const int*   adj   = (const int*)d_in[2];   // bool array delivered as int32
    const float* Wq    = (const float*)d_in[3]; // (2,5,32) -> Wq[0] at base
    const float* Mk    = (const float*)d_in[4]; // (6,5,32) -> Mk[0] at base
    const float* Mv    = (const float*)d_in[5];
    const float* R1    = (const float*)d_in[6];
    const float* rb1   = (const float*)d_in[7];
    const float* R2    = (const float*)d_in[8];
    const float* rb2   = (const float*)d_in[9];
    const float* Wo0   = (const float*)d_in[10];
    // d_in[11] Wo1 unused (vector channel is dead for the output)
    const float* gnA   = (const float*)d_in[12]; // row 0
    const float* bnA   = (const float*)d_in[13];
    const float* gnF   = (const float*)d_in[14];
    const float* bnF   = (const float*)d_in[15];
    const float* Wf1   = (const float*)d_in[16]; // (2,5,20) -> Wf1[0]
    const float* Wf2   = (const float*)d_in[17]; // (2,20,5) -> Wf2[0]
    // d_in[18] gs, d_in[19] bs unused (gated vector FF is dead)
    const float* Wh1   = (const float*)d_in[20];
    const float* bh1   = (const float*)d_in[21];
    const float* Wh2   = (const float*)d_in[22];
    const float* bh2   = (const float*)d_in[23];
    float* out = (float*)d_out;

    // workspace layout (all written before read each call)
    float* q0   = (float*)d_ws;        // 512*32
    float* yk   = q0 + 512 * 32;       // 512*32
    float* yv   = yk + 512 * 32;       // 512*32
    float* xfin = yv + 512 * 32;       // 512*8 (use 5, pad to 8 for alignment)
    unsigned long long* bits = (unsigned long long*)(xfin + 512 * 8); // 512*4 u64

    hipLaunchKernelGGL(pack_adj, dim3(2), dim3(256), 0, stream, adj, bits);
    hipLaunchKernelGGL(node_prep, dim3(512), dim3(32), 0, stream,
                       feats, Wq, Mk, Mv, gnA, bnA, q0, yk, yv);
    hipLaunchKernelGGL(edge_attn, dim3(512), dim3(256), 0, stream,
                       coors, R1, rb1, R2, rb2, q0, yk, yv, bits,
                       feats, Wo0, gnF, bnF, Wf1, Wf2, xfin);
    hipLaunchKernelGGL(head_mlp, dim3(1), dim3(256), 0, stream,
                       xfin, Wh1, bh1, Wh2, bh2, out);
}

// Round 2
// 183.088 us; speedup vs baseline: 1.5091x; 1.5091x over previous
//
#include <hip/hip_runtime.h>
#include <math.h>

// Problem constants: B=2, N=256, C=5, H=4, DH=8, HID=32, FF=20
#define BB 2
#define NN 256
#define CC 5
#define HIDD 32

// Dead-code analysis (see round-0 notes): x1 enters as zeros => only the
// scalar (x0) channel reaches the output. We compute only phi chunks
// k00 (R2 cols 0:32) and v00 (R2 cols 192:224).

__device__ __forceinline__ float gelu_tanh(float x) {
    float x3 = x * x * x;
    return 0.5f * x * (1.0f + tanhf(0.7978845608028654f * (x + 0.044715f * x3)));
}
__device__ __forceinline__ float sgnf(float x) {
    return (x > 0.f) ? 1.f : ((x < 0.f) ? -1.f : 0.f);
}

// ---- Kernel 1: pack adjacency rows into bitmasks via wave ballot; zero pooled ----
// 128 blocks x 256 threads; one wave per row (4 rows/block).
__global__ __launch_bounds__(256) void pack_adj(const int* __restrict__ adj,
                                                unsigned long long* __restrict__ bits,
                                                float* __restrict__ pooled) {
    int tid = threadIdx.x;
    int lane = tid & 63, wave = tid >> 6;
    int row = blockIdx.x * 4 + wave;   // 0..511
    if (blockIdx.x == 0 && tid < 16) pooled[tid] = 0.f;
#pragma unroll
    for (int k = 0; k < 4; k++) {
        int v = adj[(size_t)row * NN + k * 64 + lane];
        unsigned long long m = __ballot(v != 0);
        if (lane == 0) bits[row * 4 + k] = m;
    }
}

// ---- Kernel 2: per-node prep: LN+gelu scalar norm; project q0, yk00, yv00 ----
// 64 blocks x 256 threads; 8 nodes per block (32 threads per node).
__global__ __launch_bounds__(256) void node_prep(const float* __restrict__ feats,
                          const float* __restrict__ Wq0,   // (C,32)
                          const float* __restrict__ Mk0,   // (C,32)
                          const float* __restrict__ Mv0,   // (C,32)
                          const float* __restrict__ gnA0,  // (C)
                          const float* __restrict__ bnA0,  // (C)
                          float* __restrict__ q0, float* __restrict__ yk, float* __restrict__ yv) {
    int tid = threadIdx.x;
    int node = blockIdx.x * 8 + (tid >> 5);
    int hd = tid & 31;
    const float* f = feats + node * CC;
    float n0[CC], x0n[CC];
    float mu = 0.f;
#pragma unroll
    for (int c = 0; c < CC; c++) { n0[c] = fabsf(f[c]); mu += n0[c]; }
    mu *= (1.0f / CC);
    float var = 0.f;
#pragma unroll
    for (int c = 0; c < CC; c++) { float d = n0[c] - mu; var += d * d; }
    var *= (1.0f / CC);
    float sd = sqrtf(var) + 1e-8f;
#pragma unroll
    for (int c = 0; c < CC; c++) {
        float ln = (n0[c] - mu) / sd * gnA0[c] + bnA0[c];
        x0n[c] = sgnf(f[c]) * gelu_tanh(ln);
    }
    float q = 0.f, k = 0.f, v = 0.f;
#pragma unroll
    for (int c = 0; c < CC; c++) {
        q = fmaf(x0n[c], Wq0[c * HIDD + hd], q);
        k = fmaf(x0n[c], Mk0[c * HIDD + hd], k);
        v = fmaf(x0n[c], Mv0[c * HIDD + hd], v);
    }
    q0[node * HIDD + hd] = q;
    yk[node * HIDD + hd] = k;
    yv[node * HIDD + hd] = v;
}

// ---- Kernel 3: fused edge MLP + masked softmax attention + node epilogue ----
// One block per (b,i); thread j = neighbor. Register-pressure-aware layout:
// single acc[32] reused for k and v matvecs; hidden activation recomputed
// per-w (1 fma + 1 max) instead of held live across the softmax.
__global__ __launch_bounds__(256) void edge_attn(
    const float* __restrict__ coors,
    const float* __restrict__ R1,   // (32)
    const float* __restrict__ rb1,  // (32)
    const float* __restrict__ R2,   // (32,384)
    const float* __restrict__ rb2,  // (384)
    const float* __restrict__ q0g, const float* __restrict__ ykg, const float* __restrict__ yvg,
    const unsigned long long* __restrict__ bits,
    const float* __restrict__ feats,
    const float* __restrict__ Wo0,  // (32,5)
    const float* __restrict__ gnF0, const float* __restrict__ bnF0, // (C)
    const float* __restrict__ Wf10, // (C,20)
    const float* __restrict__ Wf20, // (20,C)
    float* __restrict__ pooled)     // (2*5) accumulated node sums (pre-zeroed)
{
    int node = blockIdx.x;
    int b = node >> 8, i = node & 255;
    int tid = threadIdx.x;
    int j = tid;
    int lane = tid & 63, wave = tid >> 6;

    __shared__ float Rk[32][32];   // R2[w][0:32]
    __shared__ float Rv[32][32];   // R2[w][192:224]
    __shared__ float rbk[32], rbv[32], sR1[32], srb1[32], q0s[32];
    __shared__ unsigned long long sbits[4];
    __shared__ float wredm[4][4], wreds[4][4];
    __shared__ float hm[4], hs[4];
    __shared__ float o0w[4][32];
    __shared__ float o0s[32];

    for (int e = tid; e < 1024; e += 256) {
        int w = e >> 5, d = e & 31;
        Rk[w][d] = R2[w * 384 + d];
        Rv[w][d] = R2[w * 384 + 192 + d];
    }
    if (tid < 32) {
        rbk[tid] = rb2[tid];
        rbv[tid] = rb2[192 + tid];
        sR1[tid] = R1[tid];
        srb1[tid] = rb1[tid];
        q0s[tid] = q0g[node * 32 + tid];
    }
    if (tid < 4) sbits[tid] = bits[node * 4 + tid];
    __syncthreads();

    // dist(i,j)
    float dx = coors[(b * NN + j) * 3 + 0] - coors[(b * NN + i) * 3 + 0];
    float dy = coors[(b * NN + j) * 3 + 1] - coors[(b * NN + i) * 3 + 1];
    float dz = coors[(b * NN + j) * 3 + 2] - coors[(b * NN + i) * 3 + 2];
    float dist = sqrtf(dx * dx + dy * dy + dz * dz + 1e-12f);

    float acc[32];

    // ---- k phase: acc[hd] = sum_w relu(dist*R1[w]+rb1[w]) * Rk[w][hd] ----
#pragma unroll
    for (int hd = 0; hd < 32; hd++) acc[hd] = 0.f;
#pragma unroll 4
    for (int w = 0; w < 32; w++) {
        float hw = fmaxf(fmaf(dist, sR1[w], srb1[w]), 0.f);
#pragma unroll
        for (int hd = 0; hd < 32; hd++) acc[hd] = fmaf(hw, Rk[w][hd], acc[hd]);
    }
    const float* ykp = ykg + (size_t)(b * NN + j) * 32;
    float lg[4] = {0.f, 0.f, 0.f, 0.f};
#pragma unroll
    for (int hd = 0; hd < 32; hd++) {
        float kk = rbk[hd] + acc[hd];
        lg[hd >> 3] = fmaf(kk * q0s[hd], ykp[hd], lg[hd >> 3]);
    }

    // ---- adjacency mask: direct | shared-neighbor | diagonal ----
    {
        const unsigned long long* myb = bits + (size_t)(b * NN + j) * 4;
        bool direct = (sbits[j >> 6] >> (j & 63)) & 1ull;
        unsigned long long shr = (sbits[0] & myb[0]) | (sbits[1] & myb[1]) |
                                 (sbits[2] & myb[2]) | (sbits[3] & myb[3]);
        bool ok = direct || (shr != 0ull) || (i == j);
        const float invs = 0.35355339059327379f; // 1/sqrt(8)
#pragma unroll
        for (int h = 0; h < 4; h++) lg[h] = ok ? lg[h] * invs : -1e9f;
    }

    // ---- block softmax over j, per head ----
    float attn[4];
#pragma unroll
    for (int h = 0; h < 4; h++) {
        float v = lg[h];
        for (int off = 32; off; off >>= 1) v = fmaxf(v, __shfl_xor(v, off, 64));
        if (lane == 0) wredm[h][wave] = v;
    }
    __syncthreads();
    if (tid < 4) hm[tid] = fmaxf(fmaxf(wredm[tid][0], wredm[tid][1]), fmaxf(wredm[tid][2], wredm[tid][3]));
    __syncthreads();
#pragma unroll
    for (int h = 0; h < 4; h++) lg[h] = expf(lg[h] - hm[h]);
#pragma unroll
    for (int h = 0; h < 4; h++) {
        float v = lg[h];
        for (int off = 32; off; off >>= 1) v += __shfl_xor(v, off, 64);
        if (lane == 0) wreds[h][wave] = v;
    }
    __syncthreads();
    if (tid < 4) hs[tid] = wreds[tid][0] + wreds[tid][1] + wreds[tid][2] + wreds[tid][3];
    __syncthreads();
#pragma unroll
    for (int h = 0; h < 4; h++) attn[h] = lg[h] / hs[h];

    // ---- v phase: acc[hd] = sum_w hw * Rv[w][hd] (hidden recomputed) ----
#pragma unroll
    for (int hd = 0; hd < 32; hd++) acc[hd] = 0.f;
#pragma unroll 4
    for (int w = 0; w < 32; w++) {
        float hw = fmaxf(fmaf(dist, sR1[w], srb1[w]), 0.f);
#pragma unroll
        for (int hd = 0; hd < 32; hd++) acc[hd] = fmaf(hw, Rv[w][hd], acc[hd]);
    }
    const float* yvp = yvg + (size_t)(b * NN + j) * 32;
#pragma unroll
    for (int hd = 0; hd < 32; hd++) {
        float pv = attn[hd >> 3] * (rbv[hd] + acc[hd]) * yvp[hd];
        for (int off = 32; off; off >>= 1) pv += __shfl_xor(pv, off, 64);
        if (lane == 0) o0w[wave][hd] = pv;
    }
    __syncthreads();
    if (tid < 32) o0s[tid] = o0w[0][tid] + o0w[1][tid] + o0w[2][tid] + o0w[3][tid];
    __syncthreads();

    // ---- per-node epilogue on thread 0: out-proj, residual, LN+gelu, FF, residual;
    //      accumulate final scalars into pooled[b*5+c] ----
    if (tid == 0) {
        float x0a[5];
#pragma unroll
        for (int c = 0; c < 5; c++) {
            float d0 = 0.f;
            for (int hd = 0; hd < 32; hd++) d0 = fmaf(o0s[hd], Wo0[hd * 5 + c], d0);
            x0a[c] = feats[node * 5 + c] + d0;
        }
        float n0[5], mu = 0.f;
#pragma unroll
        for (int c = 0; c < 5; c++) { n0[c] = fabsf(x0a[c]); mu += n0[c]; }
        mu *= 0.2f;
        float var = 0.f;
#pragma unroll
        for (int c = 0; c < 5; c++) { float d = n0[c] - mu; var += d * d; }
        var *= 0.2f;
        float sd = sqrtf(var) + 1e-8f;
        float xf[5];
#pragma unroll
        for (int c = 0; c < 5; c++) {
            float ln = (n0[c] - mu) / sd * gnF0[c] + bnF0[c];
            xf[c] = sgnf(x0a[c]) * gelu_tanh(ln);
        }
        float h0[20];
        for (int f = 0; f < 20; f++) {
            float s = 0.f;
#pragma unroll
            for (int c = 0; c < 5; c++) s = fmaf(xf[c], Wf10[c * 20 + f], s);
            h0[f] = gelu_tanh(s);
        }
#pragma unroll
        for (int c = 0; c < 5; c++) {
            float f0 = 0.f;
            for (int f = 0; f < 20; f++) f0 = fmaf(h0[f], Wf20[f * 5 + c], f0);
            atomicAdd(&pooled[b * 5 + c], x0a[c] + f0);
        }
    }
}

// ---- Kernel 4: MLP head from pooled sums ----
__global__ __launch_bounds__(256) void head_mlp(const float* __restrict__ pooled,
                         const float* __restrict__ Wh1, const float* __restrict__ bh1,
                         const float* __restrict__ Wh2, const float* __restrict__ bh2,
                         float* __restrict__ out) {
    __shared__ float hdn[2][128];
    int tid = threadIdx.x;
    {
        int b = tid >> 7, k = tid & 127;
        float s = bh1[k];
#pragma unroll
        for (int c = 0; c < 5; c++)
            s = fmaf(pooled[b * 5 + c] * (1.0f / NN), Wh1[c * 128 + k], s);
        hdn[b][k] = fmaxf(s, 0.f);
    }
    __syncthreads();
    if (tid < 18) {
        int b = tid / 9, o = tid % 9;
        float s = bh2[o];
        for (int k = 0; k < 128; k++) s = fmaf(hdn[b][k], Wh2[k * 9 + o], s);
        out[b * 9 + o] = s;
    }
}

extern "C" void kernel_launch(void* const* d_in, const int* in_sizes, int n_in,
                              void* d_out, int out_size, void* d_ws, size_t ws_size,
                              hipStream_t stream) {
    const float* feats = (const float*)d_in[0];
    const float* coors = (const float*)d_in[1];
    const int*   adj   = (const int*)d_in[2];
    const float* Wq    = (const float*)d_in[3];
    const float* Mk    = (const float*)d_in[4];
    const float* Mv    = (const float*)d_in[5];
    const float* R1    = (const float*)d_in[6];
    const float* rb1   = (const float*)d_in[7];
    const float* R2    = (const float*)d_in[8];
    const float* rb2   = (const float*)d_in[9];
    const float* Wo0   = (const float*)d_in[10];
    const float* gnA   = (const float*)d_in[12];
    const float* bnA   = (const float*)d_in[13];
    const float* gnF   = (const float*)d_in[14];
    const float* bnF   = (const float*)d_in[15];
    const float* Wf1   = (const float*)d_in[16];
    const float* Wf2   = (const float*)d_in[17];
    const float* Wh1   = (const float*)d_in[20];
    const float* bh1   = (const float*)d_in[21];
    const float* Wh2   = (const float*)d_in[22];
    const float* bh2   = (const float*)d_in[23];
    float* out = (float*)d_out;

    float* q0     = (float*)d_ws;          // 512*32
    float* yk     = q0 + 512 * 32;         // 512*32
    float* yv     = yk + 512 * 32;         // 512*32
    float* pooled = yv + 512 * 32;         // 16
    unsigned long long* bits = (unsigned long long*)(pooled + 16); // 512*4

    hipLaunchKernelGGL(pack_adj, dim3(128), dim3(256), 0, stream, adj, bits, pooled);
    hipLaunchKernelGGL(node_prep, dim3(64), dim3(256), 0, stream,
                       feats, Wq, Mk, Mv, gnA, bnA, q0, yk, yv);
    hipLaunchKernelGGL(edge_attn, dim3(512), dim3(256), 0, stream,
                       coors, R1, rb1, R2, rb2, q0, yk, yv, bits,
                       feats, Wo0, gnF, bnF, Wf1, Wf2, pooled);
    hipLaunchKernelGGL(head_mlp, dim3(1), dim3(256), 0, stream,
                       pooled, Wh1, bh1, Wh2, bh2, out);
}

// Round 3
// 132.286 us; speedup vs baseline: 2.0887x; 1.3840x over previous
//
#include <hip/hip_runtime.h>
#include <math.h>

// Problem constants: B=2, N=256, C=5, H=4, DH=8, HID=32, FF=20
#define BB 2
#define NN 256
#define CC 5
#define HIDD 32

// Dead-code analysis (round-0): x1 enters as zeros => only the scalar (x0)
// channel reaches the output. Only phi chunks k00 (R2 cols 0:32) and v00
// (R2 cols 192:224) matter.
//
// Round-3 key transform: the edge MLP output is piecewise-LINEAR in dist
// (32 shared ReLU knots t[w] = -rb1[w]/R1[w]). Precompute per-bin tables
// A,B (k-phase) and C,D (v-phase): k00[hd] = dist*A_p[hd] + B_p[hd].

__device__ __forceinline__ float gelu_tanh(float x) {
    float x3 = x * x * x;
    return 0.5f * x * (1.0f + tanhf(0.7978845608028654f * (x + 0.044715f * x3)));
}
__device__ __forceinline__ float sgnf(float x) {
    return (x > 0.f) ? 1.f : ((x < 0.f) ? -1.f : 0.f);
}

#define TROW 9           // table row = 9 float4 = 36 floats (32 used + pad)
#define TSZ (33 * TROW)  // one table, in float4 units

// ---- Kernel 1 (fused prep): adjacency bitmasks | node projections | PWL table ----
__global__ __launch_bounds__(256) void prep(
    const int* __restrict__ adj,
    const float* __restrict__ feats,
    const float* __restrict__ Wq0, const float* __restrict__ Mk0, const float* __restrict__ Mv0,
    const float* __restrict__ gnA0, const float* __restrict__ bnA0,
    const float* __restrict__ R1, const float* __restrict__ rb1,
    const float* __restrict__ R2, const float* __restrict__ rb2,
    unsigned long long* __restrict__ bits,
    float* __restrict__ q0, float* __restrict__ yk, float* __restrict__ yv,
    float* __restrict__ table,   // 4 * 33 * 36 floats
    float* __restrict__ tsg)     // 32 sorted knots
{
    int bid = blockIdx.x;
    int tid = threadIdx.x;

    if (bid < 128) {
        // ---- pack adjacency: 4 rows per block via wave ballot ----
        int lane = tid & 63, wave = tid >> 6;
        int row = bid * 4 + wave;
#pragma unroll
        for (int k = 0; k < 4; k++) {
            int v = adj[(size_t)row * NN + k * 64 + lane];
            unsigned long long m = __ballot(v != 0);
            if (lane == 0) bits[row * 4 + k] = m;
        }
    } else if (bid < 192) {
        // ---- node prep: LN+gelu scalar norm; project q0, yk00, yv00 ----
        int node = (bid - 128) * 8 + (tid >> 5);
        int hd = tid & 31;
        const float* f = feats + node * CC;
        float n0[CC], x0n[CC];
        float mu = 0.f;
#pragma unroll
        for (int c = 0; c < CC; c++) { n0[c] = fabsf(f[c]); mu += n0[c]; }
        mu *= (1.0f / CC);
        float var = 0.f;
#pragma unroll
        for (int c = 0; c < CC; c++) { float d = n0[c] - mu; var += d * d; }
        var *= (1.0f / CC);
        float sd = sqrtf(var) + 1e-8f;
#pragma unroll
        for (int c = 0; c < CC; c++) {
            float ln = (n0[c] - mu) / sd * gnA0[c] + bnA0[c];
            x0n[c] = sgnf(f[c]) * gelu_tanh(ln);
        }
        float q = 0.f, k = 0.f, v = 0.f;
#pragma unroll
        for (int c = 0; c < CC; c++) {
            q = fmaf(x0n[c], Wq0[c * HIDD + hd], q);
            k = fmaf(x0n[c], Mk0[c * HIDD + hd], k);
            v = fmaf(x0n[c], Mv0[c * HIDD + hd], v);
        }
        q0[node * HIDD + hd] = q;
        yk[node * HIDD + hd] = k;
        yv[node * HIDD + hd] = v;
    } else {
        // ---- build piecewise-linear tables ----
        __shared__ float sR1[32], srb1[32], tt[32], ts[32], reps[33];
        if (tid < 32) { sR1[tid] = R1[tid]; srb1[tid] = rb1[tid]; }
        __syncthreads();
        if (tid < 32) {
            float r = sR1[tid];
            // R1==0: activity is dist-independent (rb1 sign); knot position irrelevant
            tt[tid] = (r != 0.f) ? (-srb1[tid] / r) : -3.0e38f;
        }
        __syncthreads();
        if (tid < 32) {
            float t = tt[tid];
            int rank = 0;
            for (int k = 0; k < 32; k++) {
                float tk = tt[k];
                rank += (tk < t) || (tk == t && k < tid);
            }
            ts[rank] = t;
        }
        __syncthreads();
        if (tid < 33) {
            float rep;
            if (tid == 0) rep = ts[0] - 1.0f;
            else if (tid == 32) rep = ts[31] + 1.0f;
            else rep = 0.5f * (ts[tid - 1] + ts[tid]);
            reps[tid] = rep;
            if (tid < 32) tsg[tid] = ts[tid];
        }
        __syncthreads();
        for (int idx = tid; idx < 33 * 32; idx += 256) {
            int p = idx >> 5, hd = idx & 31;
            float rep = reps[p];
            float A = 0.f, Bv = 0.f, Cv = 0.f, Dv = 0.f;
            for (int w = 0; w < 32; w++) {
                float r = sR1[w], bb = srb1[w];
                if (fmaf(r, rep, bb) > 0.f) {
                    float rk = R2[w * 384 + hd];
                    float rv = R2[w * 384 + 192 + hd];
                    A = fmaf(r, rk, A); Bv = fmaf(bb, rk, Bv);
                    Cv = fmaf(r, rv, Cv); Dv = fmaf(bb, rv, Dv);
                }
            }
            Bv += rb2[hd];          // fold second-layer bias
            Dv += rb2[192 + hd];
            table[0 * 33 * 36 + p * 36 + hd] = A;
            table[1 * 33 * 36 + p * 36 + hd] = Bv;
            table[2 * 33 * 36 + p * 36 + hd] = Cv;
            table[3 * 33 * 36 + p * 36 + hd] = Dv;
        }
    }
}

// ---- Kernel 2: edge attention via PWL table + masked softmax + node epilogue ----
// One block per (b,i); thread j = neighbor.
__global__ __launch_bounds__(256) void edge_attn(
    const float* __restrict__ coors,
    const float* __restrict__ q0g, const float* __restrict__ ykg, const float* __restrict__ yvg,
    const unsigned long long* __restrict__ bits,
    const float* __restrict__ feats,
    const float* __restrict__ Wo0,  // (32,5)
    const float* __restrict__ gnF0, const float* __restrict__ bnF0,
    const float* __restrict__ Wf10, // (C,20)
    const float* __restrict__ Wf20, // (20,C)
    const float* __restrict__ table, const float* __restrict__ tsg,
    float* __restrict__ xfin)       // (512,5) final scalar features
{
    int node = blockIdx.x;
    int b = node >> 8, i = node & 255;
    int tid = threadIdx.x;
    int j = tid;
    int lane = tid & 63, wave = tid >> 6;

    __shared__ float4 sT[4 * TSZ];          // A|B|C|D tables, rows padded to 9 f4
    __shared__ float sts[32], q0s[32];
    __shared__ float Wo0t[5][32];
    __shared__ unsigned long long sbits[4];
    __shared__ float wredm[4][4], wreds[4][4], hm[4], hs[4];
    __shared__ float ew[4][5], x0as[5], xfs[5], h0s[20];

    {
        const float4* tg = (const float4*)table;
        for (int idx = tid; idx < 4 * TSZ; idx += 256) sT[idx] = tg[idx];
    }
    if (tid < 32) { sts[tid] = tsg[tid]; q0s[tid] = q0g[node * 32 + tid]; }
    if (tid < 160) Wo0t[tid / 32][tid % 32] = Wo0[(tid % 32) * 5 + tid / 32];
    if (tid < 4) sbits[tid] = bits[node * 4 + tid];
    __syncthreads();

    // dist(i,j)
    float dx = coors[(b * NN + j) * 3 + 0] - coors[(b * NN + i) * 3 + 0];
    float dy = coors[(b * NN + j) * 3 + 1] - coors[(b * NN + i) * 3 + 1];
    float dz = coors[(b * NN + j) * 3 + 2] - coors[(b * NN + i) * 3 + 2];
    float dist = sqrtf(dx * dx + dy * dy + dz * dz + 1e-12f);

    // bin index: p = #{k: ts[k] < dist}
    int p = 0;
#pragma unroll
    for (int k = 0; k < 32; k++) p += (sts[k] < dist) ? 1 : 0;

    const float4* Ap = sT + 0 * TSZ + p * TROW;
    const float4* Bp = sT + 1 * TSZ + p * TROW;
    const float4* Cp = sT + 2 * TSZ + p * TROW;
    const float4* Dp = sT + 3 * TSZ + p * TROW;
    const float4* ykp = (const float4*)(ykg + (size_t)(b * NN + j) * 32);
    const float4* yvp = (const float4*)(yvg + (size_t)(b * NN + j) * 32);
    const float4* q04 = (const float4*)q0s;

    // logits: lg[h] = sum_hd (dist*A+B)[hd] * q0[hd] * yk[j][hd]
    float lg[4] = {0.f, 0.f, 0.f, 0.f};
#pragma unroll
    for (int q = 0; q < 8; q++) {
        float4 a = Ap[q], bb = Bp[q], y = ykp[q], qq = q04[q];
        int h = q >> 1;
        lg[h] = fmaf(fmaf(dist, a.x, bb.x) * qq.x, y.x, lg[h]);
        lg[h] = fmaf(fmaf(dist, a.y, bb.y) * qq.y, y.y, lg[h]);
        lg[h] = fmaf(fmaf(dist, a.z, bb.z) * qq.z, y.z, lg[h]);
        lg[h] = fmaf(fmaf(dist, a.w, bb.w) * qq.w, y.w, lg[h]);
    }

    // adjacency mask: direct | shared-neighbor | diagonal
    {
        const unsigned long long* myb = bits + (size_t)(b * NN + j) * 4;
        bool direct = (sbits[j >> 6] >> (j & 63)) & 1ull;
        unsigned long long shr = (sbits[0] & myb[0]) | (sbits[1] & myb[1]) |
                                 (sbits[2] & myb[2]) | (sbits[3] & myb[3]);
        bool ok = direct || (shr != 0ull) || (i == j);
        const float invs = 0.35355339059327379f; // 1/sqrt(8)
#pragma unroll
        for (int h = 0; h < 4; h++) lg[h] = ok ? lg[h] * invs : -1e9f;
    }

    // block softmax over j, per head
    float attn[4];
#pragma unroll
    for (int h = 0; h < 4; h++) {
        float v = lg[h];
        for (int off = 32; off; off >>= 1) v = fmaxf(v, __shfl_xor(v, off, 64));
        if (lane == 0) wredm[h][wave] = v;
    }
    __syncthreads();
    if (tid < 4) hm[tid] = fmaxf(fmaxf(wredm[tid][0], wredm[tid][1]), fmaxf(wredm[tid][2], wredm[tid][3]));
    __syncthreads();
#pragma unroll
    for (int h = 0; h < 4; h++) lg[h] = expf(lg[h] - hm[h]);
#pragma unroll
    for (int h = 0; h < 4; h++) {
        float v = lg[h];
        for (int off = 32; off; off >>= 1) v += __shfl_xor(v, off, 64);
        if (lane == 0) wreds[h][wave] = v;
    }
    __syncthreads();
    if (tid < 4) hs[tid] = wreds[tid][0] + wreds[tid][1] + wreds[tid][2] + wreds[tid][3];
    __syncthreads();
#pragma unroll
    for (int h = 0; h < 4; h++) attn[h] = lg[h] / hs[h];

    // v-phase with Wo0 folded: e[c] = sum_hd attn*(dist*C+D)[hd]*yv[hd]*Wo0[hd][c]
    float e[5] = {0.f, 0.f, 0.f, 0.f, 0.f};
#pragma unroll
    for (int q = 0; q < 8; q++) {
        float4 c4 = Cp[q], d4 = Dp[q], y = yvp[q];
        float at = attn[q >> 1];
        float4 pv;
        pv.x = at * fmaf(dist, c4.x, d4.x) * y.x;
        pv.y = at * fmaf(dist, c4.y, d4.y) * y.y;
        pv.z = at * fmaf(dist, c4.z, d4.z) * y.z;
        pv.w = at * fmaf(dist, c4.w, d4.w) * y.w;
#pragma unroll
        for (int c = 0; c < 5; c++) {
            float4 w4 = ((const float4*)Wo0t[c])[q];
            e[c] = fmaf(pv.x, w4.x, fmaf(pv.y, w4.y, fmaf(pv.z, w4.z, fmaf(pv.w, w4.w, e[c]))));
        }
    }
    // block-reduce e[0..4]
    for (int off = 32; off; off >>= 1)
#pragma unroll
        for (int c = 0; c < 5; c++) e[c] += __shfl_xor(e[c], off, 64);
    if (lane == 0)
#pragma unroll
        for (int c = 0; c < 5; c++) ew[wave][c] = e[c];
    __syncthreads();

    // epilogue, parallel across lanes
    if (tid < 5) {
        float d0 = ew[0][tid] + ew[1][tid] + ew[2][tid] + ew[3][tid];
        x0as[tid] = feats[node * 5 + tid] + d0;
    }
    __syncthreads();
    if (tid < 5) {
        float x0a[5], n0[5];
        float mu = 0.f;
#pragma unroll
        for (int c = 0; c < 5; c++) { x0a[c] = x0as[c]; n0[c] = fabsf(x0a[c]); mu += n0[c]; }
        mu *= 0.2f;
        float var = 0.f;
#pragma unroll
        for (int c = 0; c < 5; c++) { float d = n0[c] - mu; var += d * d; }
        var *= 0.2f;
        float sd = sqrtf(var) + 1e-8f;
        float ln = (n0[tid] - mu) / sd * gnF0[tid] + bnF0[tid];
        xfs[tid] = sgnf(x0a[tid]) * gelu_tanh(ln);
    }
    __syncthreads();
    if (tid < 20) {
        float s = 0.f;
#pragma unroll
        for (int c = 0; c < 5; c++) s = fmaf(xfs[c], Wf10[c * 20 + tid], s);
        h0s[tid] = gelu_tanh(s);
    }
    __syncthreads();
    if (tid < 5) {
        float f0 = 0.f;
        for (int f = 0; f < 20; f++) f0 = fmaf(h0s[f], Wf20[f * 5 + tid], f0);
        xfin[node * 5 + tid] = x0as[tid] + f0;
    }
}

// ---- Kernel 3: mean-pool + 2-layer MLP head ----
__global__ __launch_bounds__(256) void head_mlp(const float* __restrict__ xfin,
                         const float* __restrict__ Wh1, const float* __restrict__ bh1,
                         const float* __restrict__ Wh2, const float* __restrict__ bh2,
                         float* __restrict__ out) {
    __shared__ float part[2][5][25];
    __shared__ float pooled[10];
    __shared__ float hdn[2][128];
    int tid = threadIdx.x;
    if (tid < 250) {
        int b = tid / 125, r = tid % 125, c = r / 25, grp = r % 25;
        float s = 0.f;
        for (int i = grp; i < NN; i += 25) s += xfin[(b * NN + i) * 5 + c];
        part[b][c][grp] = s;
    }
    __syncthreads();
    if (tid < 10) {
        int b = tid / 5, c = tid % 5;
        float s = 0.f;
        for (int g = 0; g < 25; g++) s += part[b][c][g];
        pooled[tid] = s * (1.0f / NN);
    }
    __syncthreads();
    {
        int b = tid >> 7, k = tid & 127;
        float s = bh1[k];
#pragma unroll
        for (int c = 0; c < 5; c++) s = fmaf(pooled[b * 5 + c], Wh1[c * 128 + k], s);
        hdn[b][k] = fmaxf(s, 0.f);
    }
    __syncthreads();
    if (tid < 18) {
        int b = tid / 9, o = tid % 9;
        float s = bh2[o];
        for (int k = 0; k < 128; k++) s = fmaf(hdn[b][k], Wh2[k * 9 + o], s);
        out[b * 9 + o] = s;
    }
}

extern "C" void kernel_launch(void* const* d_in, const int* in_sizes, int n_in,
                              void* d_out, int out_size, void* d_ws, size_t ws_size,
                              hipStream_t stream) {
    const float* feats = (const float*)d_in[0];
    const float* coors = (const float*)d_in[1];
    const int*   adj   = (const int*)d_in[2];
    const float* Wq    = (const float*)d_in[3];
    const float* Mk    = (const float*)d_in[4];
    const float* Mv    = (const float*)d_in[5];
    const float* R1    = (const float*)d_in[6];
    const float* rb1   = (const float*)d_in[7];
    const float* R2    = (const float*)d_in[8];
    const float* rb2   = (const float*)d_in[9];
    const float* Wo0   = (const float*)d_in[10];
    const float* gnA   = (const float*)d_in[12];
    const float* bnA   = (const float*)d_in[13];
    const float* gnF   = (const float*)d_in[14];
    const float* bnF   = (const float*)d_in[15];
    const float* Wf1   = (const float*)d_in[16];
    const float* Wf2   = (const float*)d_in[17];
    const float* Wh1   = (const float*)d_in[20];
    const float* bh1   = (const float*)d_in[21];
    const float* Wh2   = (const float*)d_in[22];
    const float* bh2   = (const float*)d_in[23];
    float* out = (float*)d_out;

    // workspace layout (floats unless noted); keep 16B alignment for table
    float* q0    = (float*)d_ws;             // 512*32
    float* yk    = q0 + 512 * 32;            // 512*32
    float* yv    = yk + 512 * 32;            // 512*32
    float* xfin  = yv + 512 * 32;            // 512*5 -> pad 512*8
    float* tsg   = xfin + 512 * 8;           // 32
    unsigned long long* bits = (unsigned long long*)(tsg + 32); // 512*4 u64
    float* table = (float*)(bits + 512 * 4); // 4*33*36

    hipLaunchKernelGGL(prep, dim3(193), dim3(256), 0, stream,
                       adj, feats, Wq, Mk, Mv, gnA, bnA, R1, rb1, R2, rb2,
                       bits, q0, yk, yv, table, tsg);
    hipLaunchKernelGGL(edge_attn, dim3(512), dim3(256), 0, stream,
                       coors, q0, yk, yv, bits, feats, Wo0, gnF, bnF, Wf1, Wf2,
                       table, tsg, xfin);
    hipLaunchKernelGGL(head_mlp, dim3(1), dim3(256), 0, stream,
                       xfin, Wh1, bh1, Wh2, bh2, out);
}